// Round 1
// 444.411 us; speedup vs baseline: 1.0745x; 1.0745x over previous
//
#include <hip/hip_runtime.h>
#include <stdint.h>
#include <stddef.h>

#define N_NODES 10000
#define N_EDGES 160000
#define IN_CH   768
#define TYPE_DIM 128
#define D1      896     // IN_CH + TYPE_DIM
#define HID     768
#define N_REL   3
#define NB      (N_NODES * N_REL)   // 30000 (node,relation) buckets

typedef _Float16 f16;
typedef _Float16 f16x4 __attribute__((ext_vector_type(4)));
typedef _Float16 f16x8 __attribute__((ext_vector_type(8)));
typedef float    f32x4 __attribute__((ext_vector_type(4)));

// ---------------------------------------------------------------- utilities
__global__ void zero_ints(int* __restrict__ a, int n) {
    int i = blockIdx.x * 256 + threadIdx.x;
    if (i < n) a[i] = 0;
}

// h0 (f16) = concat(x, node_emb[type]) -> H [10000][896]
__global__ void concat_f16(const float* __restrict__ x, const int* __restrict__ node_type,
                           const float* __restrict__ node_emb, f16* __restrict__ H) {
    int tid = blockIdx.x * 256 + threadIdx.x;
    int n = tid / (D1 / 4);
    int c = (tid % (D1 / 4)) * 4;
    if (n >= N_NODES) return;
    float4 v;
    if (c < IN_CH) v = *(const float4*)(x + (size_t)n * IN_CH + c);
    else           v = *(const float4*)(node_emb + (size_t)node_type[n] * TYPE_DIM + (c - IN_CH));
    f16x4 o; o[0] = (f16)v.x; o[1] = (f16)v.y; o[2] = (f16)v.z; o[3] = (f16)v.w;
    *(f16x4*)(H + (size_t)n * D1 + c) = o;
}

__global__ void count_kernel(const int* __restrict__ ei, const int* __restrict__ et,
                             int* __restrict__ counts) {
    int e = blockIdx.x * 256 + threadIdx.x;
    if (e >= N_EDGES) return;
    atomicAdd(&counts[ei[N_EDGES + e] * N_REL + et[e]], 1);
}

__global__ void scan_kernel(const int* __restrict__ counts, int* __restrict__ row_ptr) {
    __shared__ int part[1024];
    int t = threadIdx.x;
    const int CH = (NB + 1023) / 1024;   // 30
    int s = 0;
    for (int i = 0; i < CH; i++) { int idx = t * CH + i; if (idx < NB) s += counts[idx]; }
    part[t] = s;
    __syncthreads();
    for (int off = 1; off < 1024; off <<= 1) {
        int v = part[t];
        int u = (t >= off) ? part[t - off] : 0;
        __syncthreads();
        part[t] = v + u;
        __syncthreads();
    }
    int base = (t > 0) ? part[t - 1] : 0;
    for (int i = 0; i < CH; i++) {
        int idx = t * CH + i;
        if (idx < NB) { row_ptr[idx] = base; base += counts[idx]; }
    }
    if (t == 1023) row_ptr[NB] = base;
}

__global__ void fill_kernel(const int* __restrict__ ei, const int* __restrict__ et,
                            const int* __restrict__ row_ptr, int* __restrict__ cursor,
                            int* __restrict__ entries) {
    int e = blockIdx.x * 256 + threadIdx.x;
    if (e >= N_EDGES) return;
    int b = ei[N_EDGES + e] * N_REL + et[e];
    int pos = atomicAdd(&cursor[b], 1);
    entries[row_ptr[b] + pos] = ei[e];
}

// w [K][N] fp32  ->  bt [N][ldbt] f16 at column offset koff (bt[n][koff+k] = w[k][n])
__global__ void transpose_to_f16(const float* __restrict__ w, int N,
                                 f16* __restrict__ bt, int ldbt, int koff) {
    __shared__ float t[32][33];
    int kb = blockIdx.x * 32, nb = blockIdx.y * 32;
    int tx = threadIdx.x, ty = threadIdx.y;   // (32, 8)
#pragma unroll
    for (int i = 0; i < 4; i++)
        t[ty * 4 + i][tx] = w[(size_t)(kb + ty * 4 + i) * N + nb + tx];
    __syncthreads();
#pragma unroll
    for (int i = 0; i < 4; i++)
        bt[(size_t)(nb + ty * 4 + i) * ldbt + koff + kb + tx] = (f16)t[tx][ty * 4 + i];
}

// wave-per-bucket mean aggregation: 4 buckets/block, f16x8 loads, fp32 accum,
// 4-edge unroll for memory-level parallelism (latency-bound gather)
template <int DIN>
__global__ __launch_bounds__(256) void aggregate_wave(
    const f16* __restrict__ h, const int* __restrict__ row_ptr,
    const int* __restrict__ entries, f16* __restrict__ out, const int ldout) {
    const int b = blockIdx.x * 4 + (threadIdx.x >> 6);
    const int lane = threadIdx.x & 63;
    constexpr int C2 = DIN / 8 - 64;    // 48 (896) or 32 (768)
    const int beg = row_ptr[b], end = row_ptr[b + 1];
    float a0[8], a1[8];
#pragma unroll
    for (int i = 0; i < 8; i++) { a0[i] = 0.f; a1[i] = 0.f; }
    int e = beg;
    for (; e + 4 <= end; e += 4) {
        const f16* rA = h + (size_t)entries[e] * DIN;
        const f16* rB = h + (size_t)entries[e + 1] * DIN;
        const f16* rC = h + (size_t)entries[e + 2] * DIN;
        const f16* rD = h + (size_t)entries[e + 3] * DIN;
        f16x8 vA0 = *(const f16x8*)(rA + lane * 8);
        f16x8 vB0 = *(const f16x8*)(rB + lane * 8);
        f16x8 vC0 = *(const f16x8*)(rC + lane * 8);
        f16x8 vD0 = *(const f16x8*)(rD + lane * 8);
        if (lane < C2) {
            f16x8 vA1 = *(const f16x8*)(rA + 512 + lane * 8);
            f16x8 vB1 = *(const f16x8*)(rB + 512 + lane * 8);
            f16x8 vC1 = *(const f16x8*)(rC + 512 + lane * 8);
            f16x8 vD1 = *(const f16x8*)(rD + 512 + lane * 8);
#pragma unroll
            for (int i = 0; i < 8; i++)
                a1[i] += ((float)vA1[i] + (float)vB1[i]) + ((float)vC1[i] + (float)vD1[i]);
        }
#pragma unroll
        for (int i = 0; i < 8; i++)
            a0[i] += ((float)vA0[i] + (float)vB0[i]) + ((float)vC0[i] + (float)vD0[i]);
    }
    for (; e + 2 <= end; e += 2) {
        const f16* rA = h + (size_t)entries[e] * DIN;
        const f16* rB = h + (size_t)entries[e + 1] * DIN;
        f16x8 vA0 = *(const f16x8*)(rA + lane * 8);
        f16x8 vB0 = *(const f16x8*)(rB + lane * 8);
        if (lane < C2) {
            f16x8 vA1 = *(const f16x8*)(rA + 512 + lane * 8);
            f16x8 vB1 = *(const f16x8*)(rB + 512 + lane * 8);
#pragma unroll
            for (int i = 0; i < 8; i++) { a1[i] += (float)vA1[i]; a1[i] += (float)vB1[i]; }
        }
#pragma unroll
        for (int i = 0; i < 8; i++) { a0[i] += (float)vA0[i]; a0[i] += (float)vB0[i]; }
    }
    if (e < end) {
        const f16* rA = h + (size_t)entries[e] * DIN;
        f16x8 vA0 = *(const f16x8*)(rA + lane * 8);
        if (lane < C2) {
            f16x8 vA1 = *(const f16x8*)(rA + 512 + lane * 8);
#pragma unroll
            for (int i = 0; i < 8; i++) a1[i] += (float)vA1[i];
        }
#pragma unroll
        for (int i = 0; i < 8; i++) a0[i] += (float)vA0[i];
    }
    const float s = (end > beg) ? 1.0f / (float)(end - beg) : 0.f;
    f16* o = out + (size_t)(b / N_REL) * ldout + (size_t)(b % N_REL) * DIN;
    f16x8 w0, w1;
#pragma unroll
    for (int i = 0; i < 8; i++) { w0[i] = (f16)(a0[i] * s); w1[i] = (f16)(a1[i] * s); }
    *(f16x8*)(o + lane * 8) = w0;
    if (lane < C2) *(f16x8*)(o + 512 + lane * 8) = w1;
}

// ---------------- f16 MFMA GEMM (interleaved-row 8-slot XOR layout, BK=64)
__device__ __forceinline__ void gload16(const void* g, void* l) {
    __builtin_amdgcn_global_load_lds(
        (const __attribute__((address_space(1))) unsigned int*)g,
        (__attribute__((address_space(3))) unsigned int*)l, 16, 0, 0);
}

// C = relu([A1|A2] @ BT^T + bias); f16 out (ldc16) or fp32 (d_out).
// 128x128 tile, 4 waves (2x2 of 64x64), BK=64 (two 32-wide K-halves), dbuf,
// 1-deep prefetch (= 2 K-steps of lead vs old BK=32 -> covers L3 latency),
// vmcnt(8), raw barriers, 56 barrier pairs per block (was 112).
// Each 32-wide K-half is an independent 16 KB region with the verified layout:
// LDS row r (128 B) = [A-row r 64B | B-row r 64B], 8 slots of 16B,
// phys_slot = log_slot ^ (r&7) (involution, both sides) -> bank-conflict-free.
__global__ __launch_bounds__(256) void gemm_f16_ilv(
    const f16* __restrict__ A1, const int K1,
    const f16* __restrict__ A2, const int K2,
    const f16* __restrict__ BT, const int ldbt,
    const float* __restrict__ bias,
    const int M, const int N,
    f16* __restrict__ Cf16, const int ldc16, float* __restrict__ Cf32) {
    __shared__ f16 T[2 * 16384];   // 2 bufs x 2 K-halves x 128 rows x 128 B = 64 KB

    // bijective XCD-chunk swizzle (m204); row-panel-major decode
    const int CB = N >> 7;
    const int nwg = gridDim.x;
    const int q = nwg >> 3, r = nwg & 7;
    const int orig = blockIdx.x;
    const int xcd = orig & 7, pos = orig >> 3;
    const int wg = (xcd < r ? xcd * (q + 1) : r * (q + 1) + (xcd - r) * q) + pos;
    const int x = wg / CB, y = wg - x * CB;
    const int row0 = x * 128, col0 = y * 128;

    const int tid  = threadIdx.x;
    const int lane = tid & 63;
    const int wave = tid >> 6;
    const int wr = wave >> 1, wc = wave & 1;      // 2x2 wave grid, 64x64 each
    const int l16 = lane & 15, hi = lane >> 4;
    const int key = l16 & 7;                      // read-side row XOR key (row&7 == l16&7)
    const int pAf = (hi ^ key) * 8;               // f16 offset of A frag slot within row
    const int pBf = ((4 | hi) ^ key) * 8;         // f16 offset of B frag slot

    f32x4 acc[4][4];
#pragma unroll
    for (int m = 0; m < 4; m++)
#pragma unroll
        for (int n = 0; n < 4; n++) acc[m][n] = (f32x4){0.f, 0.f, 0.f, 0.f};

    // staging (per K-half): chunk c = tid + 256j (j=0..3): row = c>>3, phys
    // slot = c&7, LDS byte = c*16 (linear -> valid gload_lds dest). Logical
    // slot sl = (c&7) ^ (row&7) is per-thread constant; sl<4 -> A, else B.
    // K-half h adds +32 f16 to the source column and +8192 f16 to the dest.
    const int r_  = tid >> 3;                  // 0..31
    const int sl  = (tid & 7) ^ (r_ & 7);
    const bool isA = sl < 4;
    const int colA = sl * 8;                   // f16 col within a 32-wide K-half
    const int colB = (sl - 4) * 8;
    const f16* pLo[4]; const f16* pHi[4];
#pragma unroll
    for (int j = 0; j < 4; j++) {
        const int rr = r_ + 32 * j;
        if (isA) {
            pLo[j] = A1 + (size_t)(row0 + rr) * K1 + colA;
            pHi[j] = A2 + (size_t)(row0 + rr) * K2 + colA - K1;
        } else {
            pLo[j] = BT + (size_t)(col0 + rr) * ldbt + colB;
            pHi[j] = pLo[j];
        }
    }

    const int KT = K1 + K2;
    const int nt = KT >> 6;      // BK = 64; all K1/K2 here are multiples of 64

#define STAGE(t) do {                                                  \
        const int k0_ = (t) * 64;                                      \
        f16* l_ = T + ((t) & 1) * 16384 + tid * 8;                     \
        _Pragma("unroll")                                              \
        for (int j = 0; j < 4; j++) {                                  \
            const f16* s_ = ((k0_ < K1) ? pLo[j] : pHi[j]) + k0_;      \
            gload16(s_,      l_ + j * 2048);                           \
            gload16(s_ + 32, l_ + 8192 + j * 2048);                    \
        }                                                              \
    } while (0)

    STAGE(0);
    for (int t = 0; t < nt; ++t) {
        if (t + 1 < nt) {
            STAGE(t + 1);                                     // next tile in flight
            asm volatile("s_waitcnt vmcnt(8)" ::: "memory");  // current tile landed
        } else {
            asm volatile("s_waitcnt vmcnt(0)" ::: "memory");
        }
        __builtin_amdgcn_s_barrier();                         // tile t visible to all

        const f16* Tb = T + (t & 1) * 16384;
        f16x8 af[2][4], bf[2][4];
#pragma unroll
        for (int h = 0; h < 2; h++) {
#pragma unroll
            for (int m = 0; m < 4; m++)
                af[h][m] = *(const f16x8*)(Tb + h * 8192 + (wr * 64 + m * 16 + l16) * 64 + pAf);
#pragma unroll
            for (int n = 0; n < 4; n++)
                bf[h][n] = *(const f16x8*)(Tb + h * 8192 + (wc * 64 + n * 16 + l16) * 64 + pBf);
        }
#pragma unroll
        for (int h = 0; h < 2; h++)
#pragma unroll
            for (int m = 0; m < 4; m++)
#pragma unroll
                for (int n = 0; n < 4; n++)
                    acc[m][n] = __builtin_amdgcn_mfma_f32_16x16x32_f16(af[h][m], bf[h][n], acc[m][n], 0, 0, 0);

        asm volatile("s_barrier" ::: "memory");               // reads done -> buf reusable
    }
#undef STAGE

    const int hi4 = hi * 4;
#pragma unroll
    for (int m = 0; m < 4; m++) {
#pragma unroll
        for (int n = 0; n < 4; n++) {
            const int col = col0 + wc * 64 + n * 16 + l16;
            const float bv = bias[col];
#pragma unroll
            for (int rr2 = 0; rr2 < 4; rr2++) {
                const int row = row0 + wr * 64 + m * 16 + hi4 + rr2;
                if (row < M) {
                    float v = acc[m][n][rr2] + bv;
                    v = v > 0.f ? v : 0.f;
                    if (Cf16) Cf16[(size_t)row * ldc16 + col] = (f16)v;
                    else      Cf32[(size_t)row * N + col] = v;
                }
            }
        }
    }
}

// ---------------------------------------------------------------- launch
extern "C" void kernel_launch(void* const* d_in, const int* in_sizes, int n_in,
                              void* d_out, int out_size, void* d_ws, size_t ws_size,
                              hipStream_t stream) {
    const float* x         = (const float*)d_in[0];
    const int*   node_type = (const int*)d_in[1];
    const int*   ei        = (const int*)d_in[2];
    const int*   et        = (const int*)d_in[3];
    const float* node_emb  = (const float*)d_in[4];
    const float* w_rel1    = (const float*)d_in[5];  // [2688,896]
    const float* w_root1   = (const float*)d_in[6];  // [896,896]
    const float* b1        = (const float*)d_in[7];
    const float* w_rel2    = (const float*)d_in[8];  // [2688,768]
    const float* w_root2   = (const float*)d_in[9];  // [896,768]
    const float* b2        = (const float*)d_in[10];
    const float* w_rel3    = (const float*)d_in[11]; // [2304,768]
    const float* w_root3   = (const float*)d_in[12]; // [768,768]
    const float* b3        = (const float*)d_in[13];

    // workspace layout (~107.3 MB; harness ws proven >= 180 MB in round 1)
    char* ws = (char*)d_ws;
    f16* AGG = (f16*)(ws + 0);                 // [10000][2688] f16 = 53,760,000
    f16* Ha  = (f16*)(ws + 53760000);          // [10000][896] f16  = 17,920,000
    f16* Hb  = (f16*)(ws + 71680000);          // [10000][896] f16  = 17,920,000
    f16* BT1 = (f16*)(ws + 89600000);          // [896][3584]  = 6,422,528
    f16* BT2 = (f16*)(ws + 96022528);          // [768][3584]  = 5,505,024
    f16* BT3 = (f16*)(ws + 101527552);         // [768][3072]  = 4,718,592
    int* counts  = (int*)(ws + 106246144);     // 30000
    int* cursor  = (int*)(ws + 106366144);     // 30000
    int* row_ptr = (int*)(ws + 106486144);     // 30001
    int* entries = (int*)(ws + 106606148);     // 160000

    // graph prep
    zero_ints<<<(2 * NB + 255) / 256, 256, 0, stream>>>(counts, 2 * NB);
    concat_f16<<<(N_NODES * (D1 / 4)) / 256 + 1, 256, 0, stream>>>(x, node_type, node_emb, Ha);
    count_kernel<<<N_EDGES / 256, 256, 0, stream>>>(ei, et, counts);
    scan_kernel<<<1, 1024, 0, stream>>>(counts, row_ptr);
    fill_kernel<<<N_EDGES / 256, 256, 0, stream>>>(ei, et, row_ptr, cursor, entries);

    // weights -> combined BT f16
    {
        dim3 b(32, 8);
        transpose_to_f16<<<dim3(2688 / 32, 896 / 32), b, 0, stream>>>(w_rel1, 896, BT1, 3584, 0);
        transpose_to_f16<<<dim3(896 / 32, 896 / 32), b, 0, stream>>>(w_root1, 896, BT1, 3584, 2688);
        transpose_to_f16<<<dim3(2688 / 32, 768 / 32), b, 0, stream>>>(w_rel2, 768, BT2, 3584, 0);
        transpose_to_f16<<<dim3(896 / 32, 768 / 32), b, 0, stream>>>(w_root2, 768, BT2, 3584, 2688);
        transpose_to_f16<<<dim3(2304 / 32, 768 / 32), b, 0, stream>>>(w_rel3, 768, BT3, 3072, 0);
        transpose_to_f16<<<dim3(768 / 32, 768 / 32), b, 0, stream>>>(w_root3, 768, BT3, 3072, 2304);
    }

    const int RB = (N_NODES + 127) / 128;   // 79

    // layer 1: [AGG(2688)|h0(896)] @ BT1 -> h1 (f16) into Hb
    aggregate_wave<D1><<<NB / 4, 256, 0, stream>>>(Ha, row_ptr, entries, AGG, 2688);
    gemm_f16_ilv<<<RB * 7, 256, 0, stream>>>(AGG, 2688, Ha, 896, BT1, 3584, b1,
                                             N_NODES, 896, Hb, 896, nullptr);
    // layer 2: [AGG(2688)|h1(896)] @ BT2 -> h2 (f16) into Ha (as [10000][768])
    aggregate_wave<D1><<<NB / 4, 256, 0, stream>>>(Hb, row_ptr, entries, AGG, 2688);
    gemm_f16_ilv<<<RB * 6, 256, 0, stream>>>(AGG, 2688, Hb, 896, BT2, 3584, b2,
                                             N_NODES, 768, Ha, 768, nullptr);
    // layer 3: [AGG(2304)|h2(768)] @ BT3 -> d_out (fp32)
    aggregate_wave<HID><<<NB / 4, 256, 0, stream>>>(Ha, row_ptr, entries, AGG, 2304);
    gemm_f16_ilv<<<RB * 6, 256, 0, stream>>>(AGG, 2304, Ha, 768, BT3, 3072, b3,
                                             N_NODES, 768, nullptr, 0, (float*)d_out);
}

// Round 2
// 427.242 us; speedup vs baseline: 1.1177x; 1.0402x over previous
//
#include <hip/hip_runtime.h>
#include <stdint.h>
#include <stddef.h>

#define N_NODES 10000
#define N_EDGES 160000
#define IN_CH   768
#define TYPE_DIM 128
#define D1      896     // IN_CH + TYPE_DIM
#define HID     768
#define N_REL   3
#define NB      (N_NODES * N_REL)   // 30000 (node,relation) buckets

typedef _Float16 f16;
typedef _Float16 f16x4 __attribute__((ext_vector_type(4)));
typedef _Float16 f16x8 __attribute__((ext_vector_type(8)));
typedef float    f32x4 __attribute__((ext_vector_type(4)));

// ---------------------------------------------------------------- utilities
__global__ void zero_ints(int* __restrict__ a, int n) {
    int i = blockIdx.x * 256 + threadIdx.x;
    if (i < n) a[i] = 0;
}

// h0 (f16) = concat(x, node_emb[type]) -> H [10000][896]
__global__ void concat_f16(const float* __restrict__ x, const int* __restrict__ node_type,
                           const float* __restrict__ node_emb, f16* __restrict__ H) {
    int tid = blockIdx.x * 256 + threadIdx.x;
    int n = tid / (D1 / 4);
    int c = (tid % (D1 / 4)) * 4;
    if (n >= N_NODES) return;
    float4 v;
    if (c < IN_CH) v = *(const float4*)(x + (size_t)n * IN_CH + c);
    else           v = *(const float4*)(node_emb + (size_t)node_type[n] * TYPE_DIM + (c - IN_CH));
    f16x4 o; o[0] = (f16)v.x; o[1] = (f16)v.y; o[2] = (f16)v.z; o[3] = (f16)v.w;
    *(f16x4*)(H + (size_t)n * D1 + c) = o;
}

__global__ void count_kernel(const int* __restrict__ ei, const int* __restrict__ et,
                             int* __restrict__ counts) {
    int e = blockIdx.x * 256 + threadIdx.x;
    if (e >= N_EDGES) return;
    atomicAdd(&counts[ei[N_EDGES + e] * N_REL + et[e]], 1);
}

__global__ void scan_kernel(const int* __restrict__ counts, int* __restrict__ row_ptr) {
    __shared__ int part[1024];
    int t = threadIdx.x;
    const int CH = (NB + 1023) / 1024;   // 30
    int s = 0;
    for (int i = 0; i < CH; i++) { int idx = t * CH + i; if (idx < NB) s += counts[idx]; }
    part[t] = s;
    __syncthreads();
    for (int off = 1; off < 1024; off <<= 1) {
        int v = part[t];
        int u = (t >= off) ? part[t - off] : 0;
        __syncthreads();
        part[t] = v + u;
        __syncthreads();
    }
    int base = (t > 0) ? part[t - 1] : 0;
    for (int i = 0; i < CH; i++) {
        int idx = t * CH + i;
        if (idx < NB) { row_ptr[idx] = base; base += counts[idx]; }
    }
    if (t == 1023) row_ptr[NB] = base;
}

__global__ void fill_kernel(const int* __restrict__ ei, const int* __restrict__ et,
                            const int* __restrict__ row_ptr, int* __restrict__ cursor,
                            int* __restrict__ entries) {
    int e = blockIdx.x * 256 + threadIdx.x;
    if (e >= N_EDGES) return;
    int b = ei[N_EDGES + e] * N_REL + et[e];
    int pos = atomicAdd(&cursor[b], 1);
    entries[row_ptr[b] + pos] = ei[e];
}

// w [K][N] fp32  ->  bt [N][ldbt] f16 at column offset koff (bt[n][koff+k] = w[k][n])
__global__ void transpose_to_f16(const float* __restrict__ w, int N,
                                 f16* __restrict__ bt, int ldbt, int koff) {
    __shared__ float t[32][33];
    int kb = blockIdx.x * 32, nb = blockIdx.y * 32;
    int tx = threadIdx.x, ty = threadIdx.y;   // (32, 8)
#pragma unroll
    for (int i = 0; i < 4; i++)
        t[ty * 4 + i][tx] = w[(size_t)(kb + ty * 4 + i) * N + nb + tx];
    __syncthreads();
#pragma unroll
    for (int i = 0; i < 4; i++)
        bt[(size_t)(nb + ty * 4 + i) * ldbt + koff + kb + tx] = (f16)t[tx][ty * 4 + i];
}

// wave-per-bucket mean aggregation: 4 buckets/block, f16x8 loads, fp32 accum,
// 4-edge unroll for memory-level parallelism (latency-bound gather)
template <int DIN>
__global__ __launch_bounds__(256) void aggregate_wave(
    const f16* __restrict__ h, const int* __restrict__ row_ptr,
    const int* __restrict__ entries, f16* __restrict__ out, const int ldout) {
    const int b = blockIdx.x * 4 + (threadIdx.x >> 6);
    const int lane = threadIdx.x & 63;
    constexpr int C2 = DIN / 8 - 64;    // 48 (896) or 32 (768)
    const int beg = row_ptr[b], end = row_ptr[b + 1];
    float a0[8], a1[8];
#pragma unroll
    for (int i = 0; i < 8; i++) { a0[i] = 0.f; a1[i] = 0.f; }
    int e = beg;
    for (; e + 4 <= end; e += 4) {
        const f16* rA = h + (size_t)entries[e] * DIN;
        const f16* rB = h + (size_t)entries[e + 1] * DIN;
        const f16* rC = h + (size_t)entries[e + 2] * DIN;
        const f16* rD = h + (size_t)entries[e + 3] * DIN;
        f16x8 vA0 = *(const f16x8*)(rA + lane * 8);
        f16x8 vB0 = *(const f16x8*)(rB + lane * 8);
        f16x8 vC0 = *(const f16x8*)(rC + lane * 8);
        f16x8 vD0 = *(const f16x8*)(rD + lane * 8);
        if (lane < C2) {
            f16x8 vA1 = *(const f16x8*)(rA + 512 + lane * 8);
            f16x8 vB1 = *(const f16x8*)(rB + 512 + lane * 8);
            f16x8 vC1 = *(const f16x8*)(rC + 512 + lane * 8);
            f16x8 vD1 = *(const f16x8*)(rD + 512 + lane * 8);
#pragma unroll
            for (int i = 0; i < 8; i++)
                a1[i] += ((float)vA1[i] + (float)vB1[i]) + ((float)vC1[i] + (float)vD1[i]);
        }
#pragma unroll
        for (int i = 0; i < 8; i++)
            a0[i] += ((float)vA0[i] + (float)vB0[i]) + ((float)vC0[i] + (float)vD0[i]);
    }
    for (; e + 2 <= end; e += 2) {
        const f16* rA = h + (size_t)entries[e] * DIN;
        const f16* rB = h + (size_t)entries[e + 1] * DIN;
        f16x8 vA0 = *(const f16x8*)(rA + lane * 8);
        f16x8 vB0 = *(const f16x8*)(rB + lane * 8);
        if (lane < C2) {
            f16x8 vA1 = *(const f16x8*)(rA + 512 + lane * 8);
            f16x8 vB1 = *(const f16x8*)(rB + 512 + lane * 8);
#pragma unroll
            for (int i = 0; i < 8; i++) { a1[i] += (float)vA1[i]; a1[i] += (float)vB1[i]; }
        }
#pragma unroll
        for (int i = 0; i < 8; i++) { a0[i] += (float)vA0[i]; a0[i] += (float)vB0[i]; }
    }
    if (e < end) {
        const f16* rA = h + (size_t)entries[e] * DIN;
        f16x8 vA0 = *(const f16x8*)(rA + lane * 8);
        if (lane < C2) {
            f16x8 vA1 = *(const f16x8*)(rA + 512 + lane * 8);
#pragma unroll
            for (int i = 0; i < 8; i++) a1[i] += (float)vA1[i];
        }
#pragma unroll
        for (int i = 0; i < 8; i++) a0[i] += (float)vA0[i];
    }
    const float s = (end > beg) ? 1.0f / (float)(end - beg) : 0.f;
    f16* o = out + (size_t)(b / N_REL) * ldout + (size_t)(b % N_REL) * DIN;
    f16x8 w0, w1;
#pragma unroll
    for (int i = 0; i < 8; i++) { w0[i] = (f16)(a0[i] * s); w1[i] = (f16)(a1[i] * s); }
    *(f16x8*)(o + lane * 8) = w0;
    if (lane < C2) *(f16x8*)(o + 512 + lane * 8) = w1;
}

// ---------------- f16 MFMA GEMM (interleaved-row 8-slot XOR layout, BK=64, 8 waves)
__device__ __forceinline__ void gload16(const void* g, void* l) {
    __builtin_amdgcn_global_load_lds(
        (const __attribute__((address_space(1))) unsigned int*)g,
        (__attribute__((address_space(3))) unsigned int*)l, 16, 0, 0);
}

// C = relu([A1|A2] @ BT^T + bias); f16 out (ldc16) or fp32 (d_out).
// 128x128 tile, 8 waves (2x4 of 64x32), BK=64 (two 32-wide K-halves), dbuf,
// 1-deep prefetch, vmcnt(4), raw barriers. Grid is fixed at ~2.16 blocks/CU
// (LDS 64KB -> 2 blocks/CU), so 8 waves/block gives 4 waves/SIMD (was 2) --
// TLP to hide the barrier drain at constant grid.
// Each 32-wide K-half is an independent 16 KB region with the verified layout:
// LDS row r (128 B) = [A-row r 64B | B-row r 64B], 8 slots of 16B,
// phys_slot = log_slot ^ (r&7) (involution, both sides) -> bank-conflict-free.
__global__ __launch_bounds__(512, 4) void gemm_f16_ilv(
    const f16* __restrict__ A1, const int K1,
    const f16* __restrict__ A2, const int K2,
    const f16* __restrict__ BT, const int ldbt,
    const float* __restrict__ bias,
    const int M, const int N,
    f16* __restrict__ Cf16, const int ldc16, float* __restrict__ Cf32) {
    __shared__ f16 T[2 * 16384];   // 2 bufs x 2 K-halves x 128 rows x 128 B = 64 KB

    // bijective XCD-chunk swizzle (m204); row-panel-major decode
    const int CB = N >> 7;
    const int nwg = gridDim.x;
    const int q = nwg >> 3, r = nwg & 7;
    const int orig = blockIdx.x;
    const int xcd = orig & 7, pos = orig >> 3;
    const int wg = (xcd < r ? xcd * (q + 1) : r * (q + 1) + (xcd - r) * q) + pos;
    const int x = wg / CB, y = wg - x * CB;
    const int row0 = x * 128, col0 = y * 128;

    const int tid  = threadIdx.x;
    const int lane = tid & 63;
    const int wave = tid >> 6;
    const int wr = wave >> 2, wc = wave & 3;      // 2x4 wave grid, 64x32 each
    const int l16 = lane & 15, hi = lane >> 4;
    const int key = l16 & 7;                      // read-side row XOR key (row&7 == l16&7)
    const int pAf = (hi ^ key) * 8;               // f16 offset of A frag slot within row
    const int pBf = ((4 | hi) ^ key) * 8;         // f16 offset of B frag slot

    f32x4 acc[4][2];
#pragma unroll
    for (int m = 0; m < 4; m++)
#pragma unroll
        for (int n = 0; n < 2; n++) acc[m][n] = (f32x4){0.f, 0.f, 0.f, 0.f};

    // staging (per K-half): chunk c = tid + 512j (j=0..1): row = c>>3, phys
    // slot = c&7, LDS byte = c*16 (linear -> valid gload_lds dest). Logical
    // slot sl = (c&7) ^ (row&7) is per-thread constant (j adds 64 rows, row&7
    // unchanged); sl<4 -> A data, else B data.
    // K-half h adds +32 f16 to the source column and +8192 f16 to the dest.
    const int r_  = tid >> 3;                  // 0..63
    const int sl  = (tid & 7) ^ (r_ & 7);
    const bool isA = sl < 4;
    const int colA = sl * 8;                   // f16 col within a 32-wide K-half
    const int colB = (sl - 4) * 8;
    const f16* pLo[2]; const f16* pHi[2];
#pragma unroll
    for (int j = 0; j < 2; j++) {
        const int rr = r_ + 64 * j;
        if (isA) {
            pLo[j] = A1 + (size_t)(row0 + rr) * K1 + colA;
            pHi[j] = A2 + (size_t)(row0 + rr) * K2 + colA - K1;
        } else {
            pLo[j] = BT + (size_t)(col0 + rr) * ldbt + colB;
            pHi[j] = pLo[j];
        }
    }

    const int KT = K1 + K2;
    const int nt = KT >> 6;      // BK = 64; all K1/K2 here are multiples of 64

#define STAGE(t) do {                                                  \
        const int k0_ = (t) * 64;                                      \
        f16* l_ = T + ((t) & 1) * 16384 + tid * 8;                     \
        _Pragma("unroll")                                              \
        for (int j = 0; j < 2; j++) {                                  \
            const f16* s_ = ((k0_ < K1) ? pLo[j] : pHi[j]) + k0_;      \
            gload16(s_,      l_ + j * 4096);                           \
            gload16(s_ + 32, l_ + 8192 + j * 4096);                    \
        }                                                              \
    } while (0)

    STAGE(0);
    for (int t = 0; t < nt; ++t) {
        if (t + 1 < nt) {
            STAGE(t + 1);                                     // next tile in flight
            asm volatile("s_waitcnt vmcnt(4)" ::: "memory");  // current tile landed
        } else {
            asm volatile("s_waitcnt vmcnt(0)" ::: "memory");
        }
        __builtin_amdgcn_s_barrier();                         // tile t visible to all

        const f16* Tb = T + (t & 1) * 16384;
        f16x8 af[2][4], bf[2][2];
#pragma unroll
        for (int h = 0; h < 2; h++) {
#pragma unroll
            for (int m = 0; m < 4; m++)
                af[h][m] = *(const f16x8*)(Tb + h * 8192 + (wr * 64 + m * 16 + l16) * 64 + pAf);
#pragma unroll
            for (int n = 0; n < 2; n++)
                bf[h][n] = *(const f16x8*)(Tb + h * 8192 + (wc * 32 + n * 16 + l16) * 64 + pBf);
        }
#pragma unroll
        for (int h = 0; h < 2; h++)
#pragma unroll
            for (int m = 0; m < 4; m++)
#pragma unroll
                for (int n = 0; n < 2; n++)
                    acc[m][n] = __builtin_amdgcn_mfma_f32_16x16x32_f16(af[h][m], bf[h][n], acc[m][n], 0, 0, 0);

        asm volatile("s_barrier" ::: "memory");               // reads done -> buf reusable
    }
#undef STAGE

    const int hi4 = hi * 4;
#pragma unroll
    for (int m = 0; m < 4; m++) {
#pragma unroll
        for (int n = 0; n < 2; n++) {
            const int col = col0 + wc * 32 + n * 16 + l16;
            const float bv = bias[col];
#pragma unroll
            for (int rr2 = 0; rr2 < 4; rr2++) {
                const int row = row0 + wr * 64 + m * 16 + hi4 + rr2;
                if (row < M) {
                    float v = acc[m][n][rr2] + bv;
                    v = v > 0.f ? v : 0.f;
                    if (Cf16) Cf16[(size_t)row * ldc16 + col] = (f16)v;
                    else      Cf32[(size_t)row * N + col] = v;
                }
            }
        }
    }
}

// ---------------------------------------------------------------- launch
extern "C" void kernel_launch(void* const* d_in, const int* in_sizes, int n_in,
                              void* d_out, int out_size, void* d_ws, size_t ws_size,
                              hipStream_t stream) {
    const float* x         = (const float*)d_in[0];
    const int*   node_type = (const int*)d_in[1];
    const int*   ei        = (const int*)d_in[2];
    const int*   et        = (const int*)d_in[3];
    const float* node_emb  = (const float*)d_in[4];
    const float* w_rel1    = (const float*)d_in[5];  // [2688,896]
    const float* w_root1   = (const float*)d_in[6];  // [896,896]
    const float* b1        = (const float*)d_in[7];
    const float* w_rel2    = (const float*)d_in[8];  // [2688,768]
    const float* w_root2   = (const float*)d_in[9];  // [896,768]
    const float* b2        = (const float*)d_in[10];
    const float* w_rel3    = (const float*)d_in[11]; // [2304,768]
    const float* w_root3   = (const float*)d_in[12]; // [768,768]
    const float* b3        = (const float*)d_in[13];

    // workspace layout (~107.3 MB; harness ws proven >= 180 MB in round 1)
    char* ws = (char*)d_ws;
    f16* AGG = (f16*)(ws + 0);                 // [10000][2688] f16 = 53,760,000
    f16* Ha  = (f16*)(ws + 53760000);          // [10000][896] f16  = 17,920,000
    f16* Hb  = (f16*)(ws + 71680000);          // [10000][896] f16  = 17,920,000
    f16* BT1 = (f16*)(ws + 89600000);          // [896][3584]  = 6,422,528
    f16* BT2 = (f16*)(ws + 96022528);          // [768][3584]  = 5,505,024
    f16* BT3 = (f16*)(ws + 101527552);         // [768][3072]  = 4,718,592
    int* counts  = (int*)(ws + 106246144);     // 30000
    int* cursor  = (int*)(ws + 106366144);     // 30000
    int* row_ptr = (int*)(ws + 106486144);     // 30001
    int* entries = (int*)(ws + 106606148);     // 160000

    // graph prep
    zero_ints<<<(2 * NB + 255) / 256, 256, 0, stream>>>(counts, 2 * NB);
    concat_f16<<<(N_NODES * (D1 / 4)) / 256 + 1, 256, 0, stream>>>(x, node_type, node_emb, Ha);
    count_kernel<<<N_EDGES / 256, 256, 0, stream>>>(ei, et, counts);
    scan_kernel<<<1, 1024, 0, stream>>>(counts, row_ptr);
    fill_kernel<<<N_EDGES / 256, 256, 0, stream>>>(ei, et, row_ptr, cursor, entries);

    // weights -> combined BT f16
    {
        dim3 b(32, 8);
        transpose_to_f16<<<dim3(2688 / 32, 896 / 32), b, 0, stream>>>(w_rel1, 896, BT1, 3584, 0);
        transpose_to_f16<<<dim3(896 / 32, 896 / 32), b, 0, stream>>>(w_root1, 896, BT1, 3584, 2688);
        transpose_to_f16<<<dim3(2688 / 32, 768 / 32), b, 0, stream>>>(w_rel2, 768, BT2, 3584, 0);
        transpose_to_f16<<<dim3(896 / 32, 768 / 32), b, 0, stream>>>(w_root2, 768, BT2, 3584, 2688);
        transpose_to_f16<<<dim3(2304 / 32, 768 / 32), b, 0, stream>>>(w_rel3, 768, BT3, 3072, 0);
        transpose_to_f16<<<dim3(768 / 32, 768 / 32), b, 0, stream>>>(w_root3, 768, BT3, 3072, 2304);
    }

    const int RB = (N_NODES + 127) / 128;   // 79

    // layer 1: [AGG(2688)|h0(896)] @ BT1 -> h1 (f16) into Hb
    aggregate_wave<D1><<<NB / 4, 256, 0, stream>>>(Ha, row_ptr, entries, AGG, 2688);
    gemm_f16_ilv<<<RB * 7, 512, 0, stream>>>(AGG, 2688, Ha, 896, BT1, 3584, b1,
                                             N_NODES, 896, Hb, 896, nullptr);
    // layer 2: [AGG(2688)|h1(896)] @ BT2 -> h2 (f16) into Ha (as [10000][768])
    aggregate_wave<D1><<<NB / 4, 256, 0, stream>>>(Hb, row_ptr, entries, AGG, 2688);
    gemm_f16_ilv<<<RB * 6, 512, 0, stream>>>(AGG, 2688, Hb, 896, BT2, 3584, b2,
                                             N_NODES, 768, Ha, 768, nullptr);
    // layer 3: [AGG(2304)|h2(768)] @ BT3 -> d_out (fp32)
    aggregate_wave<HID><<<NB / 4, 256, 0, stream>>>(Ha, row_ptr, entries, AGG, 2304);
    gemm_f16_ilv<<<RB * 6, 512, 0, stream>>>(AGG, 2304, Ha, 768, BT3, 3072, b3,
                                             N_NODES, 768, nullptr, 0, (float*)d_out);
}